// Round 4
// baseline (96.031 us; speedup 1.0000x reference)
//
#include <hip/hip_runtime.h>
#include <math.h>

#define BATCH 16
#define NUM_HEADS 16
#define HEAD_DIM 64
#define HIDDEN 1024
#define BLOCK_SIZE 16
#define MAX_CTX 4096
#define BLOCKS_PER_SEQ 256
#define SPLITS 16
#define CHUNKS 4
#define CHUNK_F4 64    // (HIDDEN/CHUNKS)/4

// workspace layout in floats
#define AO_OFF   0                 // 16384
#define PML_OFF  16384             // BATCH*NUM_HEADS*SPLITS*2 = 8192
#define PO_OFF   24576             // BATCH*NUM_HEADS*SPLITS*64 = 262144
#define PART_OFF 286720            // 3072*16*CHUNKS = 196608
// total 483328 floats ~= 1.93 MB

#define LOG2E 1.4426950408889634f

// Split-K GEMV partial: rows 0..1023 -> W0, 1024..2047 -> W1, 2048..3071 -> W2.
// part layout: part[(row*16 + b)*CHUNKS + c]  -- a consumer gets all 4 chunk
// partials of one (row,b) with a single float4 load.
__global__ void proj_partial(const float* __restrict__ X,
                             const float* __restrict__ W0,
                             const float* __restrict__ W1,
                             const float* __restrict__ W2,
                             float* __restrict__ part) {
    const int tid = threadIdx.x;
    const int b = tid & 15;
    const int r = tid >> 4;                  // 0..15
    const int row = blockIdx.x * 16 + r;
    const int c = blockIdx.y;
    const int m = row >> 10;
    const int row_in = row & 1023;
    const float* W = (m == 0) ? W0 : (m == 1) ? W1 : W2;

    const float4* wrow = (const float4*)(W + (size_t)row_in * HIDDEN) + c * CHUNK_F4;
    const float4* xrow = (const float4*)(X + (size_t)b * HIDDEN) + c * CHUNK_F4;
    float acc = 0.f;
#pragma unroll 16
    for (int i = 0; i < CHUNK_F4; ++i) {
        float4 w4 = wrow[i];
        float4 x4 = xrow[i];
        acc += w4.x * x4.x + w4.y * x4.y + w4.z * x4.z + w4.w * x4.w;
    }
    part[((size_t)row * 16 + b) * CHUNKS + c] = acc;
}

// Final combine for the output projection only (rows 0..1023 -> out[b][row]).
__global__ void proj_combine(const float* __restrict__ part,
                             float* __restrict__ out) {
    const int idx = blockIdx.x * 256 + threadIdx.x;  // row*16 + b
    const int row = idx >> 4;
    const int b = idx & 15;
    const float4 p = ((const float4*)part)[idx];
    out[(size_t)b * HIDDEN + row] = p.x + p.y + p.z + p.w;
}

// issue 8 x 16B loads for 64-token iteration IT (this wave's 16-token page)
#define LOAD_KV(IT, K0, K1, K2, K3, V0, V1, V2, V3)                              \
    do {                                                                          \
        const int blk_ = bt_lds[(IT) * 4 + w];                                    \
        const size_t base_ = ((size_t)blk_ * BLOCK_SIZE + g) * 1024 + hoff;       \
        const float* kp_ = key_cache + base_;                                     \
        const float* vp_ = value_cache + base_;                                   \
        K0 = *(const float4*)(kp_);                                               \
        K1 = *(const float4*)(kp_ + 4096);                                        \
        K2 = *(const float4*)(kp_ + 8192);                                        \
        K3 = *(const float4*)(kp_ + 12288);                                       \
        V0 = *(const float4*)(vp_);                                               \
        V1 = *(const float4*)(vp_ + 4096);                                        \
        V2 = *(const float4*)(vp_ + 8192);                                        \
        V3 = *(const float4*)(vp_ + 12288);                                       \
    } while (0)

#define COMPUTE(IT, K0, K1, K2, K3, V0, V1, V2, V3)                               \
    do {                                                                          \
        float d0_ = K0.x * q4.x + K0.y * q4.y + K0.z * q4.z + K0.w * q4.w;        \
        float d1_ = K1.x * q4.x + K1.y * q4.y + K1.z * q4.z + K1.w * q4.w;        \
        float d2_ = K2.x * q4.x + K2.y * q4.y + K2.z * q4.z + K2.w * q4.w;        \
        float d3_ = K3.x * q4.x + K3.y * q4.y + K3.z * q4.z + K3.w * q4.w;        \
        d0_ += __shfl_xor(d0_, 1); d1_ += __shfl_xor(d1_, 1);                     \
        d2_ += __shfl_xor(d2_, 1); d3_ += __shfl_xor(d3_, 1);                     \
        d0_ += __shfl_xor(d0_, 2); d1_ += __shfl_xor(d1_, 2);                     \
        d2_ += __shfl_xor(d2_, 2); d3_ += __shfl_xor(d3_, 2);                     \
        d0_ += __shfl_xor(d0_, 4); d1_ += __shfl_xor(d1_, 4);                     \
        d2_ += __shfl_xor(d2_, 4); d3_ += __shfl_xor(d3_, 4);                     \
        d0_ += __shfl_xor(d0_, 8); d1_ += __shfl_xor(d1_, 8);                     \
        d2_ += __shfl_xor(d2_, 8); d3_ += __shfl_xor(d3_, 8);                     \
        const int tb_ = t0 + (IT) * 64 + w * 16 + g;                              \
        if (tb_ + 0  >= t1) d0_ = -INFINITY;                                      \
        if (tb_ + 4  >= t1) d1_ = -INFINITY;                                      \
        if (tb_ + 8  >= t1) d2_ = -INFINITY;                                      \
        if (tb_ + 12 >= t1) d3_ = -INFINITY;                                      \
        const float mx_ = fmaxf(fmaxf(d0_, d1_), fmaxf(d2_, d3_));                \
        const float m_new_ = fmaxf(m, mx_);                                       \
        const float corr_ = exp2f(m - m_new_);                                    \
        const float p0_ = exp2f(d0_ - m_new_);                                    \
        const float p1_ = exp2f(d1_ - m_new_);                                    \
        const float p2_ = exp2f(d2_ - m_new_);                                    \
        const float p3_ = exp2f(d3_ - m_new_);                                    \
        l = l * corr_ + ((p0_ + p1_) + (p2_ + p3_));                              \
        o4.x = o4.x * corr_ + p0_ * V0.x + p1_ * V1.x + p2_ * V2.x + p3_ * V3.x;  \
        o4.y = o4.y * corr_ + p0_ * V0.y + p1_ * V1.y + p2_ * V2.y + p3_ * V3.y;  \
        o4.z = o4.z * corr_ + p0_ * V0.z + p1_ * V1.z + p2_ * V2.z + p3_ * V3.z;  \
        o4.w = o4.w * corr_ + p0_ * V0.w + p1_ * V1.w + p2_ * V2.w + p3_ * V3.w;  \
        m = m_new_;                                                               \
    } while (0)

// Flash-decode partial: grid (SPLITS, NUM_HEADS, BATCH), 256 threads.
// Balanced splits: split s covers [s*chunk, min((s+1)*chunk, pos)) with
// chunk = ceil(pos / (SPLITS*64)) * 64  (<= 256 tokens, niter <= 4).
// q is combined in-prologue from the transposed projection partials.
__global__ void attn_partial(const float* __restrict__ part,
                             const float* __restrict__ key_cache,
                             const float* __restrict__ value_cache,
                             const int* __restrict__ block_table,
                             const int* __restrict__ positions,
                             float* __restrict__ part_ml,
                             float* __restrict__ part_o) {
    const int s = blockIdx.x;
    const int h = blockIdx.y;
    const int b = blockIdx.z;
    const int tid = threadIdx.x;          // 0..255
    const int lane = tid & 63;
    const int w = tid >> 6;               // wave 0..3
    const int g = lane >> 4;              // group-in-wave 0..3
    const int sub = lane & 15;            // 0..15
    const int gid = w * 4 + g;            // 0..15

    __shared__ int bt_lds[16];
    __shared__ float gm[16];
    __shared__ float gl[16];
    __shared__ float go[16][64];

    const int pos = positions[b];
    const int chunk = ((pos + SPLITS * 64 - 1) / (SPLITS * 64)) * 64;  // mult of 64
    const int t0 = s * chunk;
    const int t1 = min(t0 + chunk, pos);
    const int nvalid = t1 - t0;
    const int niter = (nvalid + 63) >> 6;

    // combine q[b][h][sub*4..sub*4+3] from 4-chunk partials (independent of LDS)
    const int hbase = h * HEAD_DIM + sub * 4;   // projection row (m=0 section)
    const float4 pq0 = ((const float4*)part)[(hbase + 0) * 16 + b];
    const float4 pq1 = ((const float4*)part)[(hbase + 1) * 16 + b];
    const float4 pq2 = ((const float4*)part)[(hbase + 2) * 16 + b];
    const float4 pq3 = ((const float4*)part)[(hbase + 3) * 16 + b];

    // stage 16 block-table entries; t0>>4 <= 240 so index <= 255: in-bounds,
    // every staged entry is a valid cache block (safe prefetch targets).
    if (tid < 16) {
        bt_lds[tid] = block_table[b * BLOCKS_PER_SEQ + (t0 >> 4) + tid];
    }
    __syncthreads();

    const float qs = 0.125f * LOG2E;   // 1/sqrt(64) * log2(e)
    float4 q4;
    q4.x = (pq0.x + pq0.y + pq0.z + pq0.w) * qs;
    q4.y = (pq1.x + pq1.y + pq1.z + pq1.w) * qs;
    q4.z = (pq2.x + pq2.y + pq2.z + pq2.w) * qs;
    q4.w = (pq3.x + pq3.y + pq3.z + pq3.w) * qs;
    const int hoff = h * HEAD_DIM + sub * 4;

    float m = -1e30f;
    float l = 0.f;
    float4 o4 = {0.f, 0.f, 0.f, 0.f};

    float4 kA0, kA1, kA2, kA3, vA0, vA1, vA2, vA3;
    float4 kB0, kB1, kB2, kB3, vB0, vB1, vB2, vB3;

    if (niter > 0) {
        LOAD_KV(0, kA0, kA1, kA2, kA3, vA0, vA1, vA2, vA3);
        int it = 0;
        while (true) {
            if (it + 1 < niter) LOAD_KV(it + 1, kB0, kB1, kB2, kB3, vB0, vB1, vB2, vB3);
            COMPUTE(it, kA0, kA1, kA2, kA3, vA0, vA1, vA2, vA3);
            ++it;
            if (it >= niter) break;
            if (it + 1 < niter) LOAD_KV(it + 1, kA0, kA1, kA2, kA3, vA0, vA1, vA2, vA3);
            COMPUTE(it, kB0, kB1, kB2, kB3, vB0, vB1, vB2, vB3);
            ++it;
            if (it >= niter) break;
        }
    }

    go[gid][sub * 4 + 0] = o4.x;
    go[gid][sub * 4 + 1] = o4.y;
    go[gid][sub * 4 + 2] = o4.z;
    go[gid][sub * 4 + 3] = o4.w;
    if (sub == 0) { gm[gid] = m; gl[gid] = l; }
    __syncthreads();

    if (tid < 64) {
        const int d = tid;
        float M = -1e30f;
#pragma unroll
        for (int gi = 0; gi < 16; ++gi) M = fmaxf(M, gm[gi]);
        float L = 0.f, O = 0.f;
#pragma unroll
        for (int gi = 0; gi < 16; ++gi) {
            const float sc = exp2f(gm[gi] - M);   // log2-domain maxes
            L += gl[gi] * sc;
            O += go[gi][d] * sc;
        }
        const int pidx = (b * NUM_HEADS + h) * SPLITS + s;
        part_o[(size_t)pidx * 64 + d] = O;
        if (d == 0) {
            part_ml[pidx * 2 + 0] = M;   // log2 domain
            part_ml[pidx * 2 + 1] = L;
        }
    }
}

// Merge split partials + the new-token (tok == pos) term. grid = B*H, 64 thr.
// q/k/v for the new token are combined from the transposed projection partials.
__global__ void attn_reduce(const float* __restrict__ part,
                            const float* __restrict__ part_ml,
                            const float* __restrict__ part_o,
                            float* __restrict__ attn_out) {
    const int bh = blockIdx.x;          // b*16 + h
    const int b = bh >> 4;
    const int h = bh & 15;
    const int d = threadIdx.x;          // 0..63

    const int row = h * HEAD_DIM + d;
    const float4 pq = ((const float4*)part)[(0    + row) * 16 + b];
    const float4 pk = ((const float4*)part)[(1024 + row) * 16 + b];
    const float4 pv = ((const float4*)part)[(2048 + row) * 16 + b];
    const float qd = pq.x + pq.y + pq.z + pq.w;
    const float kd = pk.x + pk.y + pk.z + pk.w;
    const float vd = pv.x + pv.y + pv.z + pv.w;

    float pr = qd * kd;
    pr += __shfl_xor(pr, 1);
    pr += __shfl_xor(pr, 2);
    pr += __shfl_xor(pr, 4);
    pr += __shfl_xor(pr, 8);
    pr += __shfl_xor(pr, 16);
    pr += __shfl_xor(pr, 32);
    const float s_new = pr * (0.125f * LOG2E);   // log2 domain

    float M = s_new;
#pragma unroll
    for (int sp = 0; sp < SPLITS; ++sp)
        M = fmaxf(M, part_ml[(bh * SPLITS + sp) * 2]);

    float L = exp2f(s_new - M);
    float O = L * vd;
#pragma unroll
    for (int sp = 0; sp < SPLITS; ++sp) {
        const float mg = part_ml[(bh * SPLITS + sp) * 2 + 0];
        const float lg = part_ml[(bh * SPLITS + sp) * 2 + 1];
        const float sc = exp2f(mg - M);
        L += lg * sc;
        O += part_o[(size_t)(bh * SPLITS + sp) * 64 + d] * sc;
    }
    attn_out[(size_t)b * HIDDEN + h * HEAD_DIM + d] = O / L;
}

extern "C" void kernel_launch(void* const* d_in, const int* in_sizes, int n_in,
                              void* d_out, int out_size, void* d_ws, size_t ws_size,
                              hipStream_t stream) {
    const float* hidden      = (const float*)d_in[0];
    const float* key_cache   = (const float*)d_in[1];
    const float* value_cache = (const float*)d_in[2];
    const int*   block_table = (const int*)d_in[3];
    const int*   positions   = (const int*)d_in[4];
    const float* Wq          = (const float*)d_in[5];
    const float* Wk          = (const float*)d_in[6];
    const float* Wv          = (const float*)d_in[7];
    const float* Wo          = (const float*)d_in[8];
    float* out = (float*)d_out;

    float* ws = (float*)d_ws;
    float* ao_ws = ws + AO_OFF;
    float* pml   = ws + PML_OFF;
    float* po    = ws + PO_OFF;
    float* part  = ws + PART_OFF;

    // 1) q/k/v projection partials: 3072 rows x 4 column-chunks (transposed part)
    proj_partial<<<dim3(192, CHUNKS), 256, 0, stream>>>(hidden, Wq, Wk, Wv, part);

    // 2) flash-decode partials (q combined in-prologue from part)
    attn_partial<<<dim3(SPLITS, NUM_HEADS, BATCH), 256, 0, stream>>>(
        part, key_cache, value_cache, block_table, positions, pml, po);

    // 3) merge splits + new-token contribution (q/k/v from part)
    attn_reduce<<<BATCH * NUM_HEADS, 64, 0, stream>>>(part, pml, po, ao_ws);

    // 4) output projection: 1024 rows x 4 column-chunks, then combine
    proj_partial<<<dim3(64, CHUNKS), 256, 0, stream>>>(ao_ws, Wo, Wo, Wo, part);
    proj_combine<<<64, 256, 0, stream>>>(part, out);
}